// Round 7
// baseline (4007.319 us; speedup 1.0000x reference)
//
#include <hip/hip_runtime.h>

// LSTMTagger: B=32 T=512 V=32000 E=512 H=1024 (4H=4096) O=128
// Inputs fp32/int32; output fp32. bf16 MFMA w/ fp32 accumulate for gates.
//
// Cross-WG handoff: SELF-VALIDATING TAGGED QWORDS. Each 8B packet =
// {h[2j]:bf16, h[2j+1]:bf16, tag:u32 = t+1}, stored/loaded with relaxed
// agent-scope atomics (sc0/sc1, LLC-coherent, naturally 8B-atomic). No fences,
// no flags, no producer drain: consumers retry qwords until tag matches.
// Double-buffered by (t&1); safe because WG w publishes h(t+2) only after
// consuming ALL of h(t+1), which required every WG to have consumed h(t).
// ws poison 0xAA can never equal a tag (1..512) => no init kernel needed.
//
// ws layout (bytes):
//   [0, 262144)        hbuf:  u64[4 groups][2 bufs][4096]  (tagged h pairs)
//   [262144, 327680)   vrows: ushort[32][1024]             (h at verb index)
//   [327680, 344064)   vlog:  float[32][128]

typedef short s8v __attribute__((ext_vector_type(8)));
typedef float f4v __attribute__((ext_vector_type(4)));

#define WS_VROWS_OFF 262144
#define WS_VLOG_OFF  327680

__device__ __forceinline__ float b2f(unsigned short u) {
    union { unsigned int i; float f; } x; x.i = ((unsigned int)u) << 16; return x.f;
}
__device__ __forceinline__ unsigned short f2b(float f) {
    union { float f; unsigned int i; } x; x.f = f;
    unsigned int r = (x.i + 0x7fffu + ((x.i >> 16) & 1u)) >> 16;
    return (unsigned short)r;
}
__device__ __forceinline__ float blo(unsigned int u) {
    union { unsigned int i; float f; } x; x.i = u << 16; return x.f;
}
__device__ __forceinline__ float bhi(unsigned int u) {
    union { unsigned int i; float f; } x; x.i = u & 0xffff0000u; return x.f;
}

// Distributed output projection: WG computes cols {2w,2w+1} of
// logits[b0..b0+7, tproj, :] from hA (LDS, ko-stride 17 units).
__device__ __forceinline__ void project_cols(
    const short* hA, const float* __restrict__ Wr0, const float* __restrict__ Wr1,
    float* __restrict__ dout, int b0, int tproj, int w, int tid)
{
    const int pair = tid >> 4, p = tid & 15;
    const int b = pair >> 1, oc = pair & 1;
    const float* wr = oc ? Wr1 : Wr0;
    float acc = 0.f;
#pragma unroll
    for (int j = 0; j < 8; ++j) {
        int ko = j * 16 + p;
        const unsigned int* d = (const unsigned int*)&hA[(ko * 17 + b) * 8];
        const float* wk = wr + ko * 8;
        f4v w0 = *(const f4v*)wk, w1 = *(const f4v*)(wk + 4);
        unsigned int d0 = d[0], d1 = d[1], d2 = d[2], d3 = d[3];
        acc += blo(d0) * w0[0] + bhi(d0) * w0[1] + blo(d1) * w0[2] + bhi(d1) * w0[3]
             + blo(d2) * w1[0] + bhi(d2) * w1[1] + blo(d3) * w1[2] + bhi(d3) * w1[3];
    }
#pragma unroll
    for (int off = 1; off < 16; off <<= 1) acc += __shfl_xor(acc, off);
    if (p == 0)
        dout[((size_t)(b0 + b) * 512 + tproj) * 128 + 2 * w + oc] = acc;
}

// ---------------------------------------------------------------------------
// Persistent LSTM scan. 256 WGs = 4 groups x 64 WGs; g = blk&3 (XCD affinity).
// WG w: hidden [16w,16w+16) -> 64 gate cols; wave v: cols n = gate*1024+16w+4v+(c&3).
// Per step: ONE MFMA phase (e K=512 + h K=1024, 3 chains), in-wave shfl gate
// combine + LSTM cell (c-state in lane registers), tagged qword publish,
// project(t-1), eA restage, tag-validated h restage. 2 barriers/step.
// ---------------------------------------------------------------------------
__global__ __launch_bounds__(256, 1) void scan_kernel(
    const int* __restrict__ tokens,
    const int* __restrict__ vidx,
    const float* __restrict__ emb,
    const float* __restrict__ W_ih,
    const float* __restrict__ W_hh,
    const float* __restrict__ b_ih,
    const float* __restrict__ b_hh,
    const float* __restrict__ W_lin,
    unsigned long long* __restrict__ hbuf,
    unsigned short* __restrict__ vrows,
    float* __restrict__ dout)
{
    __shared__ short hA[128 * 17 * 8];   // 34816 B (K=1024, ko-stride 17 units)
    __shared__ short eA[64 * 17 * 8];    // 17408 B (K=512)

    const int tid  = threadIdx.x;
    const int g    = blockIdx.x & 3;
    const int w    = blockIdx.x >> 2;
    const int b0   = g * 8;
    const int lane = tid & 63;
    const int v    = tid >> 6;
    const int q    = lane >> 4;
    const int c    = lane & 15;
    const int u    = c & 3;

    const float* Wr0 = W_lin + (size_t)(2 * w) * 2048 + 1024;   // Wo rows
    const float* Wr1 = W_lin + (size_t)(2 * w + 1) * 2048 + 1024;

    // --- preload B fragments, fp32 -> bf16 (VGPR-resident all 512 steps) ---
    const int n = ((c >> 2) * 1024) + 16 * w + 4 * v + u;
    s8v Bh[32], Be[16];
    {
        const float* rh = W_hh + (size_t)n * 1024;
#pragma unroll
        for (int ks = 0; ks < 32; ++ks) {
            const float* s = rh + ks * 32 + q * 8;
            f4v lo = *(const f4v*)s, hi = *(const f4v*)(s + 4);
            s8v f;
#pragma unroll
            for (int j = 0; j < 4; ++j) { f[j] = (short)f2b(lo[j]); f[j + 4] = (short)f2b(hi[j]); }
            Bh[ks] = f;
        }
        const float* re = W_ih + (size_t)n * 512;
#pragma unroll
        for (int ks = 0; ks < 16; ++ks) {
            const float* s = re + ks * 32 + q * 8;
            f4v lo = *(const f4v*)s, hi = *(const f4v*)(s + 4);
            s8v f;
#pragma unroll
            for (int j = 0; j < 4; ++j) { f[j] = (short)f2b(lo[j]); f[j + 4] = (short)f2b(hi[j]); }
            Be[ks] = f;
        }
    }

    // zero ALL of hA (h(-1)=0 + MFMA pad rows) and eA (pad rows)
    const s8v zv = {0,0,0,0,0,0,0,0};
    for (int i = tid; i < 128 * 17; i += 256) *(s8v*)&hA[i * 8] = zv;
    for (int i = tid; i < 64 * 17;  i += 256) *(s8v*)&eA[i * 8] = zv;

    // per-lane cell constants: unit n0 = 16w+4v+u (valid on lanes c<4, q<2)
    float bi, bf, bg, bo;
    {
        int n0 = 16 * w + 4 * v + u;
        bi = b_ih[n0]        + b_hh[n0];
        bf = b_ih[1024 + n0] + b_hh[1024 + n0];
        bg = b_ih[2048 + n0] + b_hh[2048 + n0];
        bo = b_ih[3072 + n0] + b_hh[3072 + n0];
    }
    int vr[4];
#pragma unroll
    for (int r = 0; r < 4; ++r) vr[r] = vidx[b0 + ((4 * q + r) & 7)];
    float cst[4] = {0.f, 0.f, 0.f, 0.f};

    unsigned long long* hbq = hbuf + g * 8192;

    // stage eA for t=0
    for (int i = tid; i < 512; i += 256) {
        int ko = i >> 3, b = i & 7;
        int tok = tokens[(b0 + b) * 512 + 0];
        const float* s = emb + (size_t)tok * 512 + ko * 8;
        f4v lo = *(const f4v*)s, hi = *(const f4v*)(s + 4);
        s8v f;
#pragma unroll
        for (int j = 0; j < 4; ++j) { f[j] = (short)f2b(lo[j]); f[j + 4] = (short)f2b(hi[j]); }
        *(s8v*)&eA[(ko * 17 + b) * 8] = f;
    }

    for (int t = 0; t < 512; ++t) {
        __syncthreads();   // B1: hA=h(t-1), eA=e(t) staged; prior readers done

        // ---- MFMA: gates = e(t).W_ih^T + h(t-1).W_hh^T  (3 chains) ----
        f4v ae = {0,0,0,0}, ah0 = {0,0,0,0}, ah1 = {0,0,0,0};
#pragma unroll
        for (int ks = 0; ks < 16; ++ks) {
            s8v aE  = *(const s8v*)&eA[((ks * 4 + q) * 17 + c) * 8];
            s8v aH0 = *(const s8v*)&hA[(((2 * ks) * 4 + q) * 17 + c) * 8];
            s8v aH1 = *(const s8v*)&hA[(((2 * ks + 1) * 4 + q) * 17 + c) * 8];
            ae  = __builtin_amdgcn_mfma_f32_16x16x32_bf16(aE,  Be[ks],       ae,  0, 0, 0);
            ah0 = __builtin_amdgcn_mfma_f32_16x16x32_bf16(aH0, Bh[2 * ks],   ah0, 0, 0, 0);
            ah1 = __builtin_amdgcn_mfma_f32_16x16x32_bf16(aH1, Bh[2 * ks+1], ah1, 0, 0, 0);
        }

        // ---- in-wave gate combine + LSTM cell + tagged publish ----
        const unsigned int tagv = (unsigned int)(t + 1);
        unsigned long long* dstq = hbq + (t & 1) * 4096;
#pragma unroll
        for (int r = 0; r < 4; ++r) {
            float a0 = ae[r] + ah0[r] + ah1[r];   // my gate value (col c)
            float fv = __shfl_xor(a0, 4);         // lanes c<4: forget gate
            float gv = __shfl_xor(a0, 8);         // lanes c<4: cell gate
            float ov = __shfl_xor(fv, 8);         // lanes c<4: output gate
            float xi = a0 + bi, xf = fv + bf, xg = gv + bg, xo = ov + bo;
            float ig = 1.f / (1.f + __expf(-xi));
            float fg = 1.f / (1.f + __expf(-xf));
            float gt = 1.f - 2.f / (1.f + __expf(2.f * xg));
            float og = 1.f / (1.f + __expf(-xo));
            cst[r] = fg * cst[r] + ig * gt;
            float h = og * (1.f - 2.f / (1.f + __expf(2.f * cst[r])));
            float hh = __shfl_xor(h, 1);          // partner unit's h
            if (q < 2 && (c == 0 || c == 2)) {
                unsigned int pack = (unsigned int)f2b(h) | ((unsigned int)f2b(hh) << 16);
                int qidx = (8 * w + 2 * v + (c >> 1)) * 8 + 4 * q + r;
                __hip_atomic_store(&dstq[qidx],
                                   (unsigned long long)pack | ((unsigned long long)tagv << 32),
                                   __ATOMIC_RELAXED, __HIP_MEMORY_SCOPE_AGENT);
                if (t == vr[r])
                    *(unsigned int*)&vrows[(b0 + 4 * q + r) * 1024 + 16 * w + 4 * v + c] = pack;
            }
        }

        // ---- project logits row t-1 from hA (h(t-1)) ----
        if (t >= 1)
            project_cols(hA, Wr0, Wr1, dout, b0, t - 1, w, tid);

        __syncthreads();   // B2: all hA/eA reads done -> safe to overwrite

        // ---- stage eA <- e(t+1) (same buffer, reads done) ----
        if (t < 511) {
            for (int i = tid; i < 512; i += 256) {
                int ko = i >> 3, b = i & 7;
                int tok = tokens[(b0 + b) * 512 + t + 1];
                const float* s = emb + (size_t)tok * 512 + ko * 8;
                f4v lo = *(const f4v*)s, hi = *(const f4v*)(s + 4);
                s8v f;
#pragma unroll
                for (int j = 0; j < 4; ++j) { f[j] = (short)f2b(lo[j]); f[j + 4] = (short)f2b(hi[j]); }
                *(s8v*)&eA[(ko * 17 + b) * 8] = f;
            }
        }

        // ---- tag-validated restage: hA <- h(t) ----
        {
            const unsigned long long* src = hbq + (t & 1) * 4096;
            unsigned int pay[16];
            unsigned int got = 0;
            while (got != 0xffffu) {
#pragma unroll
                for (int i = 0; i < 16; ++i) {
                    if (!(got & (1u << i))) {
                        int ri = i >> 2, p = i & 3;
                        int row = tid + 256 * ri;        // (ko,batch) row 0..1023
                        int ko = row >> 3, bt = row & 7;
                        unsigned long long d = __hip_atomic_load(
                            &src[(4 * ko + p) * 8 + bt],
                            __ATOMIC_RELAXED, __HIP_MEMORY_SCOPE_AGENT);
                        if ((unsigned int)(d >> 32) == tagv) {
                            pay[i] = (unsigned int)d;
                            got |= (1u << i);
                        }
                    }
                }
            }
#pragma unroll
            for (int ri = 0; ri < 4; ++ri) {
                int row = tid + 256 * ri, ko = row >> 3, bt = row & 7;
                union { unsigned int uu[4]; s8v vv; } tmp;
                tmp.uu[0] = pay[4 * ri];     tmp.uu[1] = pay[4 * ri + 1];
                tmp.uu[2] = pay[4 * ri + 2]; tmp.uu[3] = pay[4 * ri + 3];
                *(s8v*)&hA[(ko * 17 + bt) * 8] = tmp.vv;
            }
        }
    }

    // ---- tail: hA now holds h(511) ----
    __syncthreads();
    project_cols(hA, Wr0, Wr1, dout, b0, 511, w, tid);
}

// ---------------------------------------------------------------------------
// vlog[b][o] = vrows[b,:] . Wv[o,:] + b_lin[o]
// ---------------------------------------------------------------------------
__global__ void verb_kernel(const unsigned short* __restrict__ vrows,
                            const float* __restrict__ W_lin,
                            const float* __restrict__ b_lin,
                            float* __restrict__ vlog)
{
    __shared__ float vrow[1024];
    int b = blockIdx.x, tid = threadIdx.x;
    for (int i = tid; i < 1024; i += 256) vrow[i] = b2f(vrows[b * 1024 + i]);
    __syncthreads();
    if (tid < 128) {
        float acc = 0.f;
        const float* wr = W_lin + (size_t)tid * 2048;
        for (int h = 0; h < 1024; ++h) acc += vrow[h] * wr[h];
        vlog[b * 128 + tid] = acc + b_lin[tid];
    }
}

// ---------------------------------------------------------------------------
// In-place: dout[b,t,:] = log_softmax(dout[b,t,:] + vlog[b,:])
// ---------------------------------------------------------------------------
__global__ void softmax_kernel(float* __restrict__ dout,
                               const float* __restrict__ vlog)
{
    int tid = threadIdx.x;
    int grow = blockIdx.x * 32 + (tid >> 3);
    int part = tid & 7;
    int b = grow >> 9;
    float* pp = dout + (size_t)grow * 128 + part * 16;
    const float* vb = vlog + b * 128 + part * 16;
    float L[16];
#pragma unroll
    for (int i = 0; i < 16; ++i) L[i] = pp[i] + vb[i];
    float m = L[0];
#pragma unroll
    for (int i = 1; i < 16; ++i) m = fmaxf(m, L[i]);
    for (int off = 1; off < 8; off <<= 1) m = fmaxf(m, __shfl_xor(m, off));
    float s = 0.f;
#pragma unroll
    for (int i = 0; i < 16; ++i) s += expf(L[i] - m);
    for (int off = 1; off < 8; off <<= 1) s += __shfl_xor(s, off);
    float lz = m + logf(s);
#pragma unroll
    for (int i = 0; i < 16; ++i) pp[i] = L[i] - lz;
}

extern "C" void kernel_launch(void* const* d_in, const int* in_sizes, int n_in,
                              void* d_out, int out_size, void* d_ws, size_t ws_size,
                              hipStream_t stream) {
    const int*   tokens = (const int*)d_in[0];
    const int*   vidx   = (const int*)d_in[1];
    const float* emb    = (const float*)d_in[2];
    const float* W_ih   = (const float*)d_in[3];
    const float* W_hh   = (const float*)d_in[4];
    const float* b_ih   = (const float*)d_in[5];
    const float* b_hh   = (const float*)d_in[6];
    const float* W_lin  = (const float*)d_in[7];
    const float* b_lin  = (const float*)d_in[8];
    float* dout = (float*)d_out;

    char* ws = (char*)d_ws;
    unsigned long long* hbuf  = (unsigned long long*)ws;
    unsigned short*     vrows = (unsigned short*)(ws + WS_VROWS_OFF);
    float*              vlog  = (float*)(ws + WS_VLOG_OFF);

    scan_kernel<<<256, 256, 0, stream>>>(tokens, vidx, emb, W_ih, W_hh, b_ih, b_hh,
                                         W_lin, hbuf, vrows, dout);
    verb_kernel<<<32, 256, 0, stream>>>(vrows, W_lin, b_lin, vlog);
    softmax_kernel<<<512, 256, 0, stream>>>(dout, vlog);
}